// Round 5
// baseline (207.454 us; speedup 1.0000x reference)
//
#include <hip/hip_runtime.h>
#include <cstddef>
#include <cstdint>

// CollectMerge: x (B, P*CO, HI, WI) fp32, loc (B, 2P, HO, WO) fp32, bias (CO) fp32
// -> out (B, CO, HO, WO) fp32. Bilinear-sample each of P planes at loc, sum over P, + bias.
constexpr int B_  = 4;
constexpr int CO_ = 80;
constexpr int PN_ = 9;
constexpr int HI_ = 128;
constexpr int WI_ = 128;
constexpr int HW_ = HI_ * WI_;   // 16384

constexpr int NTHR   = 320;                 // 5 waves
constexpr int THW    = 64;                  // hw positions per transpose unit
constexpr int TUNITS = PN_ * (HW_ / THW);   // 2304 per batch
constexpr int GPX    = 32;                  // output pixels per gather unit
constexpr int GUNITS = HW_ / GPX;           // 512 per batch

// Shared-memory union: transpose tile / gather tables / gather output staging.
union SMU {
    struct { float w[PN_][GPX][4]; int off[PN_][GPX][4]; } ab;  //  9216 B
    float    accs[GPX][81];                                     // 10368 B (odd stride)
    uint16_t tile[CO_][72];                                     // 11520 B (16B-aligned rows)
};

__device__ __forceinline__ uint16_t f2bf(float f) {
    uint32_t u = __float_as_uint(f);
    return (uint16_t)((u + 0x7fffu + ((u >> 16) & 1u)) >> 16);   // RNE
}

// Transpose+downconvert one (b, p, 64-hw chunk): x fp32 channel-major ->
// xt bf16 channel-last with per-pixel stride COP (COP=96 -> 192B, 64B-aligned chunks).
template <int COP>
__device__ __forceinline__ void t_unit(const float* __restrict__ x,
                                       uint16_t* __restrict__ xt,
                                       int b, int u, SMU* sm, int tid) {
    const int p   = u >> 8;                  // u / (HW_/THW) = u / 256
    const int hw0 = (u & 255) << 6;          // (u % 256) * 64
    const size_t plane = (size_t)(b * PN_ + p);

    const float* src = x + plane * CO_ * (size_t)HW_ + hw0;
    for (int i = tid; i < CO_ * (THW / 4); i += NTHR) {     // 1280 float4, 4/thread
        const int co = i >> 4;
        const int h4 = (i & 15) << 2;
        const float4 v = *(const float4*)(src + (size_t)co * HW_ + h4);
        ushort4 pk;
        pk.x = f2bf(v.x); pk.y = f2bf(v.y); pk.z = f2bf(v.z); pk.w = f2bf(v.w);
        *(ushort4*)&sm->tile[co][h4] = pk;
    }
    __syncthreads();
    uint16_t* dst = xt + (plane * HW_ + hw0) * COP;
    for (int i = tid; i < THW * (CO_ / 8); i += NTHR) {     // 640 dwordx4, 2/thread
        const int px = i / 10;
        const int cp = i - px * 10;
        uint4 wv;
        uint32_t* w = (uint32_t*)&wv;
#pragma unroll
        for (int j = 0; j < 4; ++j) {
            const uint32_t lo = sm->tile[cp * 8 + 2 * j][px];
            const uint32_t hi = sm->tile[cp * 8 + 2 * j + 1][px];
            w[j] = lo | (hi << 16);
        }
        *(uint4*)(dst + px * COP + cp * 8) = wv;
    }
}

// Gather+merge one (b, 32-px chunk) from bf16 channel-last xt (pixel stride COP).
template <int COP>
__device__ __forceinline__ void g_unit(const uint16_t* __restrict__ xt,
                                       const float* __restrict__ loc,
                                       const float* __restrict__ bias,
                                       float* __restrict__ out,
                                       int b, int u, SMU* sm, int tid) {
    const int hw0 = u * GPX;

    // Phase A: bilinear weights + premultiplied byte offsets per (p, pixel)
    if (tid < PN_ * GPX) {                                   // 288
        const int p    = tid >> 5;
        const int pixl = tid & 31;
        const float y = loc[(((size_t)b * PN_ + p) * 2 + 0) * HW_ + hw0 + pixl];
        const float x = loc[(((size_t)b * PN_ + p) * 2 + 1) * HW_ + hw0 + pixl];
        const float y0f = floorf(y), x0f = floorf(x);
        const int   y0 = (int)y0f,  x0 = (int)x0f;
        const float dy = y - y0f,   dx = x - x0f;
        const float w[4] = { (1.f - dy) * (1.f - dx), (1.f - dy) * dx,
                             dy * (1.f - dx),         dy * dx };
#pragma unroll
        for (int c = 0; c < 4; ++c) {
            const int yi = y0 + (c >> 1);
            const int xi = x0 + (c & 1);
            const bool valid = (yi >= 0) & (yi < HI_) & (xi >= 0) & (xi < WI_);
            const int yc = min(max(yi, 0), HI_ - 1);
            const int xc = min(max(xi, 0), WI_ - 1);
            sm->ab.w[p][pixl][c]   = valid ? w[c] : 0.f;
            sm->ab.off[p][pixl][c] = (yc * WI_ + xc) * (COP * 2);   // byte offset
        }
    }
    __syncthreads();

    // Phase B: thread (px, cg): pixel px, channels cg*8..cg*8+7, one 16B load per tap
    const int px = tid / 10;          // 0..31
    const int cg = tid - px * 10;     // 0..9

    float acc[8];
#pragma unroll
    for (int j = 0; j < 8; ++j) acc[j] = bias[cg * 8 + j];

    for (int p = 0; p < PN_; ++p) {
        const char* base = (const char*)(xt + ((size_t)b * PN_ + p) * (size_t)HW_ * COP)
                           + cg * 16;
        uint4 v[4]; float w[4];
#pragma unroll
        for (int c = 0; c < 4; ++c) {
            v[c] = *(const uint4*)(base + sm->ab.off[p][px][c]);
            w[c] = sm->ab.w[p][px][c];
        }
#pragma unroll
        for (int c = 0; c < 4; ++c) {
            const uint32_t* uu = (const uint32_t*)&v[c];
#pragma unroll
            for (int j = 0; j < 4; ++j) {
                acc[2*j]   = fmaf(__uint_as_float(uu[j] << 16),         w[c], acc[2*j]);
                acc[2*j+1] = fmaf(__uint_as_float(uu[j] & 0xffff0000u), w[c], acc[2*j+1]);
            }
        }
    }
    __syncthreads();   // done reading sm.ab before accs overwrites the union
#pragma unroll
    for (int j = 0; j < 8; ++j) sm->accs[px][cg * 8 + j] = acc[j];
    __syncthreads();

    // Phase C: coalesced channel-major write
    for (int i = tid; i < GPX * CO_; i += NTHR) {            // 8/thread
        const int co  = i >> 5;
        const int hwl = i & 31;
        out[((size_t)b * CO_ + co) * HW_ + hw0 + hwl] = sm->accs[hwl][co];
    }
}

// ---------------------------------------------------------------------------
// Pipelined pass: tb = batch to transpose (-1 none), gb = batch to gather
// (-1 none). Mixed kernels interleave 2 G-units + 9 T-units per 11 blocks
// (G first: long poles start early). No barriers, no atomics — the T and G
// parts are fully independent; the stream orders kernel K_i after K_{i-1}.
// ---------------------------------------------------------------------------
template <int COP>
__global__ __launch_bounds__(NTHR) void pipe_k(const float* __restrict__ x,
                                               const float* __restrict__ loc,
                                               const float* __restrict__ bias,
                                               float* __restrict__ out,
                                               uint16_t* __restrict__ xt,
                                               int tb, int gb) {
    __shared__ SMU sm;
    const int bid = blockIdx.x;
    const int tid = threadIdx.x;

    if (gb < 0) { t_unit<COP>(x, xt, tb, bid, &sm, tid); return; }
    if (tb < 0) { g_unit<COP>(xt, loc, bias, out, gb, bid, &sm, tid); return; }
    const int grp = bid / 11;
    const int r   = bid - grp * 11;
    if (r < 2) g_unit<COP>(xt, loc, bias, out, gb, grp * 2 + r, &sm, tid);
    else       t_unit<COP>(x, xt, tb, grp * 9 + (r - 2), &sm, tid);
}

// ---------------------------------------------------------------------------
// Fallback (workspace too small for xt): direct fp32 gather on original layout.
// ---------------------------------------------------------------------------
__global__ __launch_bounds__(256) void gather_direct_k(const float* __restrict__ xsrc,
                                                       const float* __restrict__ loc,
                                                       const float* __restrict__ bias,
                                                       float* __restrict__ out) {
    const int b   = blockIdx.x >> 10;
    const int hw0 = (blockIdx.x & 1023) << 4;
    const int tid = threadIdx.x;

    __shared__ float wts[PN_][16][4];
    __shared__ int   idxs[PN_][16][4];
    __shared__ float accs[16][CO_ + 1];

    if (tid < PN_ * 16) {
        const int p    = tid >> 4;
        const int pixl = tid & 15;
        const float y = loc[(((size_t)b * PN_ + p) * 2 + 0) * HW_ + hw0 + pixl];
        const float x = loc[(((size_t)b * PN_ + p) * 2 + 1) * HW_ + hw0 + pixl];
        const float y0f = floorf(y), x0f = floorf(x);
        const int   y0 = (int)y0f,  x0 = (int)x0f;
        const float dy = y - y0f,   dx = x - x0f;
        const float w[4] = { (1.f - dy) * (1.f - dx), (1.f - dy) * dx,
                             dy * (1.f - dx),         dy * dx };
#pragma unroll
        for (int c = 0; c < 4; ++c) {
            const int yi = y0 + (c >> 1);
            const int xi = x0 + (c & 1);
            const bool valid = (yi >= 0) & (yi < HI_) & (xi >= 0) & (xi < WI_);
            const int yc = min(max(yi, 0), HI_ - 1);
            const int xc = min(max(xi, 0), WI_ - 1);
            wts[p][pixl][c]  = valid ? w[c] : 0.f;
            idxs[p][pixl][c] = yc * WI_ + xc;
        }
    }
    __syncthreads();

    float myacc[5];
    int   cos[5], pixls[5];
#pragma unroll
    for (int k = 0; k < 5; ++k) {
        const int item = tid + (k << 8);
        const int pixl = item / CO_;
        const int co   = item - pixl * CO_;
        cos[k] = co; pixls[k] = pixl;
        myacc[k] = bias[co];
    }
    for (int p = 0; p < PN_; ++p) {
        const float* base = xsrc + ((size_t)b * PN_ + p) * CO_ * (size_t)HW_;
#pragma unroll
        for (int k = 0; k < 5; ++k) {
#pragma unroll
            for (int c = 0; c < 4; ++c) {
                const int   idx = idxs[p][pixls[k]][c];
                const float w   = wts[p][pixls[k]][c];
                myacc[k] = fmaf(base[(size_t)cos[k] * HW_ + idx], w, myacc[k]);
            }
        }
    }
#pragma unroll
    for (int k = 0; k < 5; ++k) accs[pixls[k]][cos[k]] = myacc[k];
    __syncthreads();
    for (int i = tid; i < 16 * CO_; i += 256) {
        const int co  = i >> 4;
        const int hwl = i & 15;
        out[((size_t)b * CO_ + co) * HW_ + hw0 + hwl] = accs[hwl][co];
    }
}

template <int COP>
static void launch_pipeline(const float* x, const float* loc, const float* bias,
                            float* out, uint16_t* xt, hipStream_t stream) {
    // K0: T(0)
    pipe_k<COP><<<dim3(TUNITS), NTHR, 0, stream>>>(x, loc, bias, out, xt, 0, -1);
    // K1..K3: T(i) || G(i-1)
    for (int i = 1; i < B_; ++i)
        pipe_k<COP><<<dim3(TUNITS + GUNITS), NTHR, 0, stream>>>(x, loc, bias, out, xt, i, i - 1);
    // K4: G(3)
    pipe_k<COP><<<dim3(GUNITS), NTHR, 0, stream>>>(x, loc, bias, out, xt, -1, B_ - 1);
}

extern "C" void kernel_launch(void* const* d_in, const int* in_sizes, int n_in,
                              void* d_out, int out_size, void* d_ws, size_t ws_size,
                              hipStream_t stream) {
    const float* x    = (const float*)d_in[0];
    const float* loc  = (const float*)d_in[1];
    const float* bias = (const float*)d_in[2];
    float*       out  = (float*)d_out;

    const size_t need96 = (size_t)B_ * PN_ * HW_ * 96 * sizeof(uint16_t);   // 113.2 MB
    const size_t need80 = (size_t)B_ * PN_ * HW_ * 80 * sizeof(uint16_t);   //  94.4 MB

    if (ws_size >= need96) {
        launch_pipeline<96>(x, loc, bias, out, (uint16_t*)d_ws, stream);
    } else if (ws_size >= need80) {
        launch_pipeline<80>(x, loc, bias, out, (uint16_t*)d_ws, stream);
    } else {
        gather_direct_k<<<dim3(B_ * HW_ / 16), 256, 0, stream>>>(x, loc, bias, out);
    }
}

// Round 6
// 125.658 us; speedup vs baseline: 1.6509x; 1.6509x over previous
//
#include <hip/hip_runtime.h>
#include <cstddef>
#include <cstdint>

// CollectMerge: x (B, P*CO, HI, WI) fp32, loc (B, 2P, HO, WO) fp32, bias (CO) fp32
// -> out (B, CO, HO, WO) fp32. Bilinear-sample each of P planes at loc, sum over P, + bias.
constexpr int B_  = 4;
constexpr int CO_ = 80;
constexpr int PN_ = 9;
constexpr int HI_ = 128;
constexpr int WI_ = 128;
constexpr int HW_ = HI_ * WI_;   // 16384

__device__ __forceinline__ uint16_t f2bf(float f) {
    uint32_t u = __float_as_uint(f);
    return (uint16_t)((u + 0x7fffu + ((u >> 16) & 1u)) >> 16);   // RNE
}

// ---------------------------------------------------------------------------
// Kernel 1: transpose+downconvert x (B*P, CO, HW) fp32 -> xt (B*P, HW, CO) bf16.
// float4 global reads, ushort4 LDS writes, dwordx4 global writes.
// Batch order REVERSED (bp descending): xt(0) is written last, so it is the
// most-recently-used region of the memory-side L3 when the gather kernel
// (which consumes b=0 first) starts. Anti-aligns LRU eviction with consumption.
// ---------------------------------------------------------------------------
__global__ __launch_bounds__(256) void transpose_bf16_k(const float* __restrict__ x,
                                                        uint16_t* __restrict__ xt) {
    const int bp  = (B_ * PN_ - 1) - blockIdx.y;   // reversed batch/plane order
    const int hw0 = blockIdx.x << 7;               // 128 hw positions per block

    // row stride 136 u16 = 272B (16B-aligned rows; ds_write_b64 2-way conflicts = free)
    __shared__ uint16_t tile[CO_][136];

    const float* src = x + (size_t)bp * CO_ * HW_ + hw0;
    // read: 80 co x 32 float4 (=128 hw), 10 per thread
    for (int i = threadIdx.x; i < CO_ * 32; i += 256) {
        const int co = i >> 5;
        const int h4 = (i & 31) << 2;
        const float4 v = *(const float4*)(src + (size_t)co * HW_ + h4);
        ushort4 pk;
        pk.x = f2bf(v.x); pk.y = f2bf(v.y); pk.z = f2bf(v.z); pk.w = f2bf(v.w);
        *(ushort4*)&tile[co][h4] = pk;
    }
    __syncthreads();

    // write: 128 px x 10 dwordx4 (=160B of channels each), 5 per thread
    uint32_t* dst = (uint32_t*)(xt + ((size_t)bp * HW_ + hw0) * CO_);
    for (int i = threadIdx.x; i < 128 * 10; i += 256) {
        const int px = i / 10;
        const int cp = i - px * 10;
        uint4 wv;
        uint32_t* w = (uint32_t*)&wv;
#pragma unroll
        for (int j = 0; j < 4; ++j) {
            const uint32_t lo = tile[cp * 8 + 2 * j][px];
            const uint32_t hi = tile[cp * 8 + 2 * j + 1][px];
            w[j] = lo | (hi << 16);
        }
        *(uint4*)(dst + px * 40 + cp * 4) = wv;
    }
}

// ---------------------------------------------------------------------------
// Kernel 2: gather + merge on bf16 channel-last xt. (r2-proven structure)
// Block = 320 threads, 32 output pixels. Thread (pixl, cg): 8 channels via one
// 16B load per tap (10 lanes cover a 160B sample chunk, coalesced).
// ---------------------------------------------------------------------------
__global__ __launch_bounds__(320) void gather_bf16_k(const uint16_t* __restrict__ xt,
                                                     const float* __restrict__ loc,
                                                     const float* __restrict__ bias,
                                                     float* __restrict__ out) {
    const int b   = blockIdx.x >> 9;           // HW/32 = 512 blocks per batch
    const int hw0 = (blockIdx.x & 511) << 5;   // 32 pixels per block
    const int tid = threadIdx.x;

    __shared__ float wts[PN_][32][4];
    __shared__ int   offs[PN_][32][4];
    __shared__ float accs[32][CO_ + 1];        // stride 81: odd -> conflict-free col reads

    // Phase A: bilinear weights + premultiplied byte offsets per (p, pixel)
    if (tid < PN_ * 32) {
        const int p    = tid >> 5;
        const int pixl = tid & 31;
        const float y = loc[(((size_t)b * PN_ + p) * 2 + 0) * HW_ + hw0 + pixl];
        const float x = loc[(((size_t)b * PN_ + p) * 2 + 1) * HW_ + hw0 + pixl];
        const float y0f = floorf(y), x0f = floorf(x);
        const int   y0 = (int)y0f,  x0 = (int)x0f;
        const float dy = y - y0f,   dx = x - x0f;
        const float w[4] = { (1.f - dy) * (1.f - dx), (1.f - dy) * dx,
                             dy * (1.f - dx),         dy * dx };
#pragma unroll
        for (int c = 0; c < 4; ++c) {
            const int yi = y0 + (c >> 1);
            const int xi = x0 + (c & 1);
            const bool valid = (yi >= 0) & (yi < HI_) & (xi >= 0) & (xi < WI_);
            const int yc = min(max(yi, 0), HI_ - 1);
            const int xc = min(max(xi, 0), WI_ - 1);
            wts[p][pixl][c]  = valid ? w[c] : 0.f;
            offs[p][pixl][c] = (yc * WI_ + xc) * (CO_ * 2);   // byte offset
        }
    }
    __syncthreads();

    // Phase B: thread owns (pixl, cg): pixel pixl, channels cg*8 .. cg*8+7
    const int pixl = tid / 10;
    const int cg   = tid - pixl * 10;

    float acc[8];
#pragma unroll
    for (int j = 0; j < 8; ++j) acc[j] = bias[cg * 8 + j];

    for (int p = 0; p < PN_; ++p) {
        const char* base = (const char*)(xt + ((size_t)b * PN_ + p) * (size_t)HW_ * CO_)
                           + cg * 16;
        uint4 v[4]; float w[4];
#pragma unroll
        for (int c = 0; c < 4; ++c) {
            v[c] = *(const uint4*)(base + offs[p][pixl][c]);
            w[c] = wts[p][pixl][c];
        }
#pragma unroll
        for (int c = 0; c < 4; ++c) {
            const uint32_t* uu = (const uint32_t*)&v[c];
#pragma unroll
            for (int j = 0; j < 4; ++j) {
                acc[2*j]   = fmaf(__uint_as_float(uu[j] << 16),         w[c], acc[2*j]);
                acc[2*j+1] = fmaf(__uint_as_float(uu[j] & 0xffff0000u), w[c], acc[2*j+1]);
            }
        }
    }

#pragma unroll
    for (int j = 0; j < 8; ++j) accs[pixl][cg * 8 + j] = acc[j];
    __syncthreads();

    // Phase C: coalesced channel-major write (32 consecutive hw per co row)
    for (int i = tid; i < 32 * CO_; i += 320) {
        const int co  = i >> 5;
        const int hwl = i & 31;
        out[((size_t)b * CO_ + co) * HW_ + hw0 + hwl] = accs[hwl][co];
    }
}

// ---------------------------------------------------------------------------
// Fallback (workspace too small): direct fp32 gather on original layout.
// ---------------------------------------------------------------------------
__global__ __launch_bounds__(256) void gather_direct_k(const float* __restrict__ xsrc,
                                                       const float* __restrict__ loc,
                                                       const float* __restrict__ bias,
                                                       float* __restrict__ out) {
    const int b   = blockIdx.x >> 10;
    const int hw0 = (blockIdx.x & 1023) << 4;
    const int tid = threadIdx.x;

    __shared__ float wts[PN_][16][4];
    __shared__ int   idxs[PN_][16][4];
    __shared__ float accs[16][CO_ + 1];

    if (tid < PN_ * 16) {
        const int p    = tid >> 4;
        const int pixl = tid & 15;
        const float y = loc[(((size_t)b * PN_ + p) * 2 + 0) * HW_ + hw0 + pixl];
        const float x = loc[(((size_t)b * PN_ + p) * 2 + 1) * HW_ + hw0 + pixl];
        const float y0f = floorf(y), x0f = floorf(x);
        const int   y0 = (int)y0f,  x0 = (int)x0f;
        const float dy = y - y0f,   dx = x - x0f;
        const float w[4] = { (1.f - dy) * (1.f - dx), (1.f - dy) * dx,
                             dy * (1.f - dx),         dy * dx };
#pragma unroll
        for (int c = 0; c < 4; ++c) {
            const int yi = y0 + (c >> 1);
            const int xi = x0 + (c & 1);
            const bool valid = (yi >= 0) & (yi < HI_) & (xi >= 0) & (xi < WI_);
            const int yc = min(max(yi, 0), HI_ - 1);
            const int xc = min(max(xi, 0), WI_ - 1);
            wts[p][pixl][c]  = valid ? w[c] : 0.f;
            idxs[p][pixl][c] = yc * WI_ + xc;
        }
    }
    __syncthreads();

    float myacc[5];
    int   cos[5], pixls[5];
#pragma unroll
    for (int k = 0; k < 5; ++k) {
        const int item = tid + (k << 8);
        const int pixl = item / CO_;
        const int co   = item - pixl * CO_;
        cos[k] = co; pixls[k] = pixl;
        myacc[k] = bias[co];
    }
    for (int p = 0; p < PN_; ++p) {
        const float* base = xsrc + ((size_t)b * PN_ + p) * CO_ * (size_t)HW_;
#pragma unroll
        for (int k = 0; k < 5; ++k) {
#pragma unroll
            for (int c = 0; c < 4; ++c) {
                const int   idx = idxs[p][pixls[k]][c];
                const float w   = wts[p][pixls[k]][c];
                myacc[k] = fmaf(base[(size_t)cos[k] * HW_ + idx], w, myacc[k]);
            }
        }
    }
#pragma unroll
    for (int k = 0; k < 5; ++k) accs[pixls[k]][cos[k]] = myacc[k];
    __syncthreads();
    for (int i = tid; i < 16 * CO_; i += 256) {
        const int co  = i >> 4;
        const int hwl = i & 15;
        out[((size_t)b * CO_ + co) * HW_ + hw0 + hwl] = accs[hwl][co];
    }
}

extern "C" void kernel_launch(void* const* d_in, const int* in_sizes, int n_in,
                              void* d_out, int out_size, void* d_ws, size_t ws_size,
                              hipStream_t stream) {
    const float* x    = (const float*)d_in[0];
    const float* loc  = (const float*)d_in[1];
    const float* bias = (const float*)d_in[2];
    float*       out  = (float*)d_out;

    const size_t need = (size_t)B_ * PN_ * HW_ * CO_ * sizeof(uint16_t);   // 94.4 MB
    if (ws_size >= need) {
        uint16_t* xt = (uint16_t*)d_ws;
        dim3 g1(HW_ / 128, B_ * PN_);
        transpose_bf16_k<<<g1, 256, 0, stream>>>(x, xt);
        gather_bf16_k<<<dim3(B_ * HW_ / 32), 320, 0, stream>>>(xt, loc, bias, out);
    } else {
        gather_direct_k<<<dim3(B_ * HW_ / 16), 256, 0, stream>>>(x, loc, bias, out);
    }
}